// Round 6
// baseline (2331.531 us; speedup 1.0000x reference)
//
#include <hip/hip_runtime.h>

// SymmetricRBM — conservative VALU-only probe kernel (round 5).
// Rounds 1-4 (MFMA-based, two different fragment typings) all died at harness
// level with zero diagnostics; round-0 stub ran fine. This round deliberately
// avoids every non-vanilla feature those kernels shared: no MFMA builtins, no
// ext_vector_type, no __builtin_bit_cast, no __bf16, no __launch_bounds__, no
// hipMemsetAsync (ws zeroed by a 1-thread kernel). Pure fp32 VALU + bitmask
// state + exact JAX threefry2x32 RNG. Goal: correctness signal + baseline
// counters; re-introduce MFMA via A/B once something runs.
//
// Math (verified against reference):
//  wv[b,a,i] = sum_m k[a][(m-i)%64]   * v[b,m]        (Mf circulant)
//  wh[b,i]   = sum_{a,m} k[a][(i-1-m)%64] * h[b,a,m]  (Mb circulant)
//  One LDS table serves both: kd2[z][a] = k[a][z&63]; G1 z=m-i+64 in [1,127],
//  G2 z=i+63-m in [0,126].
//  RNG: jax.random.key(42); per step split(k,3) -> counters x0=[0,1,2],
//  x1=[3,4,5]; flat=[A.a,B.a,C.a,A.b,B.b,C.b]; k=(A.a,B.a), kh=(C.a,A.b),
//  kv=(B.b,C.b). Element e pairs with e+S/2: rows b and b+32768 share cipher
//  blocks (word0 -> b, word1 -> b+32768).
//  Thread layout: gthread = 2*pair + half; pair in [0,32768) owns rows
//  (pair, pair+32768); half owns i in [32*half, 32*half+32). Partner halves
//  are adjacent lanes -> __shfl_xor(x,1) exchange of h/v bitmask halves.

#define KSTEPS 10
#define HALF_H 8388608u   // (65536*4*64)/2
#define HALF_V 2097152u   // (65536*64)/2

__device__ __forceinline__ void tf20(unsigned int k0, unsigned int k1,
                                     unsigned int x0, unsigned int x1,
                                     unsigned int &o0, unsigned int &o1)
{
  unsigned int k2 = k0 ^ k1 ^ 0x1BD11BDAu;
  x0 += k0; x1 += k1;
#define TFR(rot) { x0 += x1; x1 = (x1 << (rot)) | (x1 >> (32 - (rot))); x1 ^= x0; }
  TFR(13) TFR(15) TFR(26) TFR(6)
  x0 += k1; x1 += k2 + 1u;
  TFR(17) TFR(29) TFR(16) TFR(24)
  x0 += k2; x1 += k0 + 2u;
  TFR(13) TFR(15) TFR(26) TFR(6)
  x0 += k0; x1 += k1 + 3u;
  TFR(17) TFR(29) TFR(16) TFR(24)
  x0 += k1; x1 += k2 + 4u;
  TFR(13) TFR(15) TFR(26) TFR(6)
  x0 += k2; x1 += k0 + 5u;
#undef TFR
  o0 = x0; o1 = x1;
}

__device__ __forceinline__ float u01(unsigned int bits) {
  // JAX uniform: bitcast(bits>>9 | 0x3f800000) - 1.0
  return __uint_as_float((bits >> 9) | 0x3F800000u) - 1.0f;
}

__device__ __forceinline__ float softplusf(float x) {
  return fmaxf(x, 0.0f) + log1pf(expf(-fabsf(x)));
}

__global__ void init_ws_kernel(float* ws) { ws[0] = 0.0f; }

__global__ void rbm_valu_kernel(const float* __restrict__ vdat,
                                const float* __restrict__ kf,
                                const float* __restrict__ bsp,
                                const float* __restrict__ cvp,
                                float* __restrict__ ws)
{
  __shared__ float kd2[128][4];          // kd2[z][a] = kf[a*64 + (z&63)], 16B rows
  __shared__ unsigned int sK[4][KSTEPS]; // kh0,kh1,kv0,kv1 per step

  const int tid = threadIdx.x;                      // 0..255
  const int gthread = blockIdx.x * 256 + tid;       // 0..65535
  const int pair = gthread >> 1;                    // rows (pair, pair+32768)
  const int half = gthread & 1;                     // i-half
  const int i0 = 32 * half;

  if (tid == 0) {
    unsigned int c0 = 0u, c1 = 42u;
    for (int t = 0; t < KSTEPS; ++t) {
      unsigned int Aa, Ab, Ba, Bb, Ca, Cb;
      tf20(c0, c1, 0u, 3u, Aa, Ab);
      tf20(c0, c1, 1u, 4u, Ba, Bb);
      tf20(c0, c1, 2u, 5u, Ca, Cb);
      sK[0][t] = Ca; sK[1][t] = Ab;   // kh
      sK[2][t] = Bb; sK[3][t] = Cb;   // kv
      c0 = Aa; c1 = Ba;               // next k
    }
  }
  for (int z = tid; z < 128; z += 256) {
    int zz = z & 63;
    kd2[z][0] = kf[zz];
    kd2[z][1] = kf[64 + zz];
    kd2[z][2] = kf[128 + zz];
    kd2[z][3] = kf[192 + zz];
  }
  __syncthreads();

  // ---- load both rows of the pair as 64-bit masks ----
  unsigned long long vm[2];
  for (int r = 0; r < 2; ++r) {
    const float* vp = vdat + (size_t)(pair + r * 32768) * 64;
    unsigned long long m = 0ull;
    for (int j = 0; j < 64; j += 4) {
      float4 f = *(const float4*)(vp + j);
      m |= ((unsigned long long)(f.x != 0.0f)) << (j + 0);
      m |= ((unsigned long long)(f.y != 0.0f)) << (j + 1);
      m |= ((unsigned long long)(f.z != 0.0f)) << (j + 2);
      m |= ((unsigned long long)(f.w != 0.0f)) << (j + 3);
    }
    vm[r] = m;
  }

  const float bs = bsp[0];
  const float cv[4] = {cvp[0], cvp[1], cvp[2], cvp[3]};

  float fe = 0.0f;  // accumulates (fe_data - fe_model) contributions
  if (half == 0)    // term1 of fe_data, counted once per pair
    fe -= bs * (float)(__popcll(vm[0]) + __popcll(vm[1]));

  unsigned long long hfull[2][4];

  for (int step = 0; step <= KSTEPS; ++step) {
    const bool fe_pass   = (step == KSTEPS);
    const bool data_pass = (step == 0);
    const unsigned int kh0 = sK[0][fe_pass ? 0 : step];
    const unsigned int kh1 = sK[1][fe_pass ? 0 : step];

    // ---- G1: wv for my i-half, both rows; softplus and/or h-sample ----
    unsigned int hmy[2][4] = {{0u,0u,0u,0u},{0u,0u,0u,0u}};
    for (int ii = 0; ii < 32; ++ii) {
      const int i = i0 + ii;
      float acc0[4] = {0.f,0.f,0.f,0.f};
      float acc1[4] = {0.f,0.f,0.f,0.f};
      for (int w = 0; w < 2; ++w) {
        unsigned int b0 = (unsigned int)(vm[0] >> (32 * w));
        unsigned int b1 = (unsigned int)(vm[1] >> (32 * w));
        const int zb = 32 * w - i + 64;
#pragma unroll
        for (int mm = 0; mm < 32; ++mm) {
          const float* kp = kd2[zb + mm];
          float f0 = (float)(b0 & 1u);
          float f1 = (float)(b1 & 1u);
          b0 >>= 1; b1 >>= 1;
          acc0[0] += f0 * kp[0]; acc0[1] += f0 * kp[1];
          acc0[2] += f0 * kp[2]; acc0[3] += f0 * kp[3];
          acc1[0] += f1 * kp[0]; acc1[1] += f1 * kp[1];
          acc1[2] += f1 * kp[2]; acc1[3] += f1 * kp[3];
        }
      }
      float x0[4], x1[4];
#pragma unroll
      for (int a = 0; a < 4; ++a) { x0[a] = acc0[a] + cv[a]; x1[a] = acc1[a] + cv[a]; }

      if (fe_pass || data_pass) {   // term2 = -sum softplus(wv + c)
        float s = 0.0f;
#pragma unroll
        for (int a = 0; a < 4; ++a) s += softplusf(x0[a]) + softplusf(x1[a]);
        fe += fe_pass ? s : -s;     // data subtracts, model pass adds back
      }
      if (!fe_pass) {
        const unsigned int base = (unsigned int)pair * 256u + (unsigned int)i;
#pragma unroll
        for (int a = 0; a < 4; ++a) {
          unsigned int cnt = base + (unsigned int)a * 64u;
          unsigned int w0, w1; tf20(kh0, kh1, cnt, cnt + HALF_H, w0, w1);
          float u0 = u01(w0), u1 = u01(w1);
          float e0 = __expf(-x0[a]), e1 = __expf(-x1[a]);
          // u < sigmoid(x)  <=>  u*(1+exp(-x)) < 1
          unsigned int d0 = (fmaf(u0, e0, u0) < 1.0f) ? 1u : 0u;
          unsigned int d1 = (fmaf(u1, e1, u1) < 1.0f) ? 1u : 0u;
          hmy[0][a] |= d0 << ii;
          hmy[1][a] |= d1 << ii;
        }
      }
    }
    if (fe_pass) break;

    // ---- exchange h halves with partner lane ----
    for (int r = 0; r < 2; ++r)
#pragma unroll
      for (int a = 0; a < 4; ++a) {
        unsigned int mine  = hmy[r][a];
        unsigned int other = (unsigned int)__shfl_xor((int)mine, 1);
        unsigned int lo = half ? other : mine;
        unsigned int hi = half ? mine  : other;
        hfull[r][a] = ((unsigned long long)hi << 32) | (unsigned long long)lo;
      }

    // ---- G2: wh for my i-half; v-sample ----
    const unsigned int kv0 = sK[2][step], kv1 = sK[3][step];
    unsigned int vmy[2] = {0u, 0u};
    for (int ii = 0; ii < 32; ++ii) {
      const int i = i0 + ii;
      float wh0 = 0.0f, wh1 = 0.0f;
      for (int w = 0; w < 2; ++w) {
        unsigned int t00 = (unsigned int)(hfull[0][0] >> (32 * w));
        unsigned int t01 = (unsigned int)(hfull[0][1] >> (32 * w));
        unsigned int t02 = (unsigned int)(hfull[0][2] >> (32 * w));
        unsigned int t03 = (unsigned int)(hfull[0][3] >> (32 * w));
        unsigned int t10 = (unsigned int)(hfull[1][0] >> (32 * w));
        unsigned int t11 = (unsigned int)(hfull[1][1] >> (32 * w));
        unsigned int t12 = (unsigned int)(hfull[1][2] >> (32 * w));
        unsigned int t13 = (unsigned int)(hfull[1][3] >> (32 * w));
        const int zb = i + 63 - 32 * w;    // z = i+63-m, descending in m
#pragma unroll
        for (int mm = 0; mm < 32; ++mm) {
          const float* kp = kd2[zb - mm];
          wh0 += (float)(t00 & 1u) * kp[0] + (float)(t01 & 1u) * kp[1]
               + (float)(t02 & 1u) * kp[2] + (float)(t03 & 1u) * kp[3];
          wh1 += (float)(t10 & 1u) * kp[0] + (float)(t11 & 1u) * kp[1]
               + (float)(t12 & 1u) * kp[2] + (float)(t13 & 1u) * kp[3];
          t00 >>= 1; t01 >>= 1; t02 >>= 1; t03 >>= 1;
          t10 >>= 1; t11 >>= 1; t12 >>= 1; t13 >>= 1;
        }
      }
      unsigned int cnt = (unsigned int)pair * 64u + (unsigned int)i;
      unsigned int w0, w1; tf20(kv0, kv1, cnt, cnt + HALF_V, w0, w1);
      float u0 = u01(w0), u1 = u01(w1);
      float e0 = __expf(-(wh0 + bs)), e1 = __expf(-(wh1 + bs));
      vmy[0] |= ((fmaf(u0, e0, u0) < 1.0f) ? 1u : 0u) << ii;
      vmy[1] |= ((fmaf(u1, e1, u1) < 1.0f) ? 1u : 0u) << ii;
    }

    // ---- exchange v halves with partner lane ----
    for (int r = 0; r < 2; ++r) {
      unsigned int mine  = vmy[r];
      unsigned int other = (unsigned int)__shfl_xor((int)mine, 1);
      unsigned int lo = half ? other : mine;
      unsigned int hi = half ? mine  : other;
      vm[r] = ((unsigned long long)hi << 32) | (unsigned long long)lo;
    }
  }

  // term1 of fe_model (v_model is current vm), once per pair
  if (half == 0)
    fe += bs * (float)(__popcll(vm[0]) + __popcll(vm[1]));

  // wave reduction, one atomic per wave
  for (int off = 32; off > 0; off >>= 1) fe += __shfl_down(fe, off);
  if ((tid & 63) == 0) atomicAdd(ws, fe);
}

__global__ void fin_kernel(const float* __restrict__ ws, float* __restrict__ out) {
  out[0] = ws[0] * (1.0f / 65536.0f);
}

extern "C" void kernel_launch(void* const* d_in, const int* in_sizes, int n_in,
                              void* d_out, int out_size, void* d_ws, size_t ws_size,
                              hipStream_t stream)
{
  (void)in_sizes; (void)n_in; (void)out_size; (void)ws_size;
  const float* vdat = (const float*)d_in[0];
  const float* kf   = (const float*)d_in[1];
  const float* bsp  = (const float*)d_in[2];
  const float* cvp  = (const float*)d_in[3];
  float* out = (float*)d_out;
  float* ws  = (float*)d_ws;

  init_ws_kernel<<<dim3(1), dim3(1), 0, stream>>>(ws);
  rbm_valu_kernel<<<dim3(256), dim3(256), 0, stream>>>(vdat, kf, bsp, cvp, ws);
  fin_kernel<<<dim3(1), dim3(1), 0, stream>>>(ws, out);
}